// Round 13
// baseline (613.593 us; speedup 1.0000x reference)
//
#include <hip/hip_runtime.h>
#include <hip/hip_bf16.h>

#define NN 100000
#define NE 3200000
#define NB 512
#define DIN 500
#define DH 64
#define HIDN 200
#define NCLS 80

#define NBUK 256
#define NPB 391
#define EPB 16384
#define NBLK_E ((NE + EPB - 1) / EPB)   // 196

typedef __attribute__((ext_vector_type(8))) short bf16x8;
typedef __attribute__((ext_vector_type(4))) float f32x4;

__device__ __forceinline__ short f2bf(float f) {
    union { float f; unsigned u; } v; v.f = f;
    unsigned r = v.u + 0x7FFF + ((v.u >> 16) & 1);   // RNE
    return (short)(r >> 16);
}
__device__ __forceinline__ float bf2f(short s) {
    union { unsigned u; float f; } v; v.u = ((unsigned)(unsigned short)s) << 16;
    return v.f;
}

// ---------- CSR pass A: per-block bucket histogram ----------
__global__ void bukhist_kernel(const int* __restrict__ dst, int* __restrict__ block_hist) {
    __shared__ int h[NBUK];
    for (int i = threadIdx.x; i < NBUK; i += 256) h[i] = 0;
    __syncthreads();
    int base = blockIdx.x * EPB;
    int end = min(base + EPB, NE);
    for (int e = base + threadIdx.x; e < end; e += 256)
        atomicAdd(&h[dst[e] / NPB], 1);
    __syncthreads();
    for (int i = threadIdx.x; i < NBUK; i += 256)
        block_hist[blockIdx.x * NBUK + i] = h[i];
}

// ---------- CSR pass B ----------
__global__ void bukoff_kernel(int* __restrict__ block_hist, int* __restrict__ buk_base) {
    __shared__ int tot[NBUK];
    __shared__ int sc[NBUK];
    int b = threadIdx.x;
    int s = 0;
    for (int i = 0; i < NBLK_E; ++i) s += block_hist[i * NBUK + b];
    tot[b] = s; sc[b] = s;
    __syncthreads();
    for (int o = 1; o < NBUK; o <<= 1) {
        int t = (b >= o) ? sc[b - o] : 0;
        __syncthreads();
        sc[b] += t;
        __syncthreads();
    }
    int excl = sc[b] - tot[b];
    buk_base[b] = excl;
    if (b == NBUK - 1) buk_base[NBUK] = excl + tot[b];
    int run = excl;
    for (int i = 0; i < NBLK_E; ++i) {
        int idx = i * NBUK + b;
        int v = block_hist[idx];
        block_hist[idx] = run;
        run += v;
    }
}

// ---------- CSR pass C ----------
__global__ void bukscat_kernel(const int* __restrict__ src, const int* __restrict__ dst,
                               const int* __restrict__ block_hist, int* __restrict__ bpack) {
    __shared__ int cur[NBUK];
    for (int i = threadIdx.x; i < NBUK; i += 256)
        cur[i] = block_hist[blockIdx.x * NBUK + i];
    __syncthreads();
    int base = blockIdx.x * EPB;
    int end = min(base + EPB, NE);
    for (int e = base + threadIdx.x; e < end; e += 256) {
        int d = dst[e];
        int bk = d / NPB;
        int p = atomicAdd(&cur[bk], 1);
        bpack[p] = (src[e] << 9) | (d - bk * NPB);
    }
}

// ---------- CSR pass D ----------
__global__ void bukfin_kernel(const int* __restrict__ buk_base, const int* __restrict__ bpack,
                              int* __restrict__ row_ptr, float* __restrict__ invdeg,
                              int* __restrict__ csr_src) {
    __shared__ int cnt[NPB];
    __shared__ int cbase[NPB];
    int bk = blockIdx.x;
    int n0 = bk * NPB;
    int nloc = min(n0 + NPB, NN) - n0;
    for (int i = threadIdx.x; i < nloc; i += 256) cnt[i] = 0;
    __syncthreads();
    int beg = buk_base[bk], end = buk_base[bk + 1];
    for (int p = beg + threadIdx.x; p < end; p += 256)
        atomicAdd(&cnt[bpack[p] & 511], 1);
    __syncthreads();
    if (threadIdx.x == 0) {
        int run = beg;
        for (int i = 0; i < nloc; ++i) { int v = cnt[i]; cbase[i] = run; run += v; }
    }
    __syncthreads();
    for (int i = threadIdx.x; i < nloc; i += 256) {
        row_ptr[n0 + i] = cbase[i];
        invdeg[n0 + i] = 1.0f / fmaxf((float)cnt[i], 1.0f);
        cnt[i] = cbase[i];
    }
    if (bk == NBUK - 1 && threadIdx.x == 0) row_ptr[NN] = end;
    __syncthreads();
    for (int p = beg + threadIdx.x; p < end; p += 256) {
        int v = bpack[p];
        int q = atomicAdd(&cnt[v & 511], 1);
        csr_src[q] = v >> 9;
    }
}

// ---------- W1 prep: fragment-major. Wf[((t*8+c)*64 + lane)*8 + i] = W[k][col],
// k = t*32 + (lane>>4)*8 + i, col = c*16 + (lane&15). Each (t,c) frag = 1KB contiguous. ----------
__global__ void wprep_frag(const float* __restrict__ Wl, const float* __restrict__ Wr,
                           short* __restrict__ Wf) {
    int id = blockIdx.x * blockDim.x + threadIdx.x;   // 16*8*64 = 8192
    if (id >= 16 * 8 * 64) return;
    int l = id & 63;
    int c = (id >> 6) & 7;
    int t = id >> 9;
    int q = l >> 4, r16 = l & 15;
    int col = c * 16 + r16;
    short v[8];
#pragma unroll
    for (int i = 0; i < 8; ++i) {
        int k = t * 32 + q * 8 + i;
        float f = 0.f;
        if (k < DIN) f = (col < 64) ? Wl[(size_t)k * 64 + col] : Wr[(size_t)k * 64 + (col - 64)];
        v[i] = f2bf(f);
    }
    *(bf16x8*)(Wf + (size_t)id * 8) = *(bf16x8*)v;
}

// ---------- W prep 64x64: Wb[col][k] ----------
__global__ void wprep64(const float* __restrict__ W, short* __restrict__ Wb) {
    int id = blockIdx.x * blockDim.x + threadIdx.x;
    if (id >= 64 * 64) return;
    int col = id >> 6, k = id & 63;
    Wb[col * 64 + k] = f2bf(W[(size_t)k * 64 + col]);
}

// ---------- conv1: zero-LDS zero-barrier direct MFMA, fragment-major B (coalesced) ----------
__launch_bounds__(256)
__global__ void gemm_direct2(const float* __restrict__ in, const short* __restrict__ Wf,
                             short* __restrict__ Hl, float* __restrict__ Hr) {
    const int tid = threadIdx.x;
    const int w = tid >> 6, l = tid & 63;
    const int q = l >> 4, r16 = l & 15;
    const int tile0 = blockIdx.x * 64 + w * 16;
    const int arow_i = tile0 + r16;
    const bool ok = arow_i < NN;
    const float* arow = in + (size_t)(ok ? arow_i : 0) * DIN + q * 8;
    const short* wf = Wf + (size_t)l * 8;      // + (t*8+c)*512 per fragment

    f32x4 acc[8];
#pragma unroll
    for (int c = 0; c < 8; ++c) acc[c] = (f32x4){0.f, 0.f, 0.f, 0.f};
    float pabs = 0.f;

#pragma unroll 2
    for (int t = 0; t < 16; ++t) {
        float v[8];
        if (t < 15) {
            const float4 f0 = *(const float4*)(arow + t * 32);
            const float4 f1 = *(const float4*)(arow + t * 32 + 4);
            v[0] = f0.x; v[1] = f0.y; v[2] = f0.z; v[3] = f0.w;
            v[4] = f1.x; v[5] = f1.y; v[6] = f1.z; v[7] = f1.w;
        } else {
#pragma unroll
            for (int i = 0; i < 8; ++i) {
                int gk = t * 32 + q * 8 + i;
                v[i] = (gk < DIN) ? arow[t * 32 + i] : 0.f;
            }
        }
        short sh[8];
#pragma unroll
        for (int i = 0; i < 8; ++i) { pabs += fabsf(v[i]); sh[i] = f2bf(v[i]); }
        bf16x8 a = *(bf16x8*)sh;
#pragma unroll
        for (int c = 0; c < 8; ++c) {
            bf16x8 b = *(const bf16x8*)(wf + ((size_t)(t * 8 + c) << 9));
            acc[c] = __builtin_amdgcn_mfma_f32_16x16x32_bf16(a, b, acc[c], 0, 0, 0);
        }
    }

    // per-row L1 inverse norm: sum the 4 k-chunk lanes (xor lane bits 4,5)
    pabs += __shfl_xor(pabs, 16, 64);
    pabs += __shfl_xor(pabs, 32, 64);
    float sval = 1.0f / fmaxf(pabs, 1e-12f);

#pragma unroll
    for (int rr = 0; rr < 4; ++rr) {
        int lrow = q * 4 + rr;                 // C/D: row=(lane>>4)*4+reg, col=lane&15
        float srow = __shfl(sval, lrow, 64);
        int grow = tile0 + lrow;
        if (grow < NN) {
#pragma unroll
            for (int c = 0; c < 8; ++c) {
                float o = acc[c][rr] * srow;
                if (c < 4) Hl[(size_t)grow * 64 + c * 16 + r16] = f2bf(o);
                else       Hr[(size_t)grow * 64 + (c - 4) * 16 + r16] = o;
            }
        }
    }
}

// ---------- conv1 gather + combine: e = sum(Hl_j)*invdeg + bl + Hr_i (bf16 out) ----------
__launch_bounds__(256)
__global__ void gather_kernel(const int* __restrict__ row_ptr, const int* __restrict__ csr_src,
                              const short* __restrict__ Hl, const float* __restrict__ Hr,
                              const float* __restrict__ invdeg, const float* __restrict__ bl,
                              short* __restrict__ ebf) {
    int node = blockIdx.x * 4 + (threadIdx.x >> 6);
    if (node >= NN) return;
    int lane = threadIdx.x & 63;
    int ng = lane >> 3;
    int fl = lane & 7;
    int beg = row_ptr[node], end = row_ptr[node + 1];
    float a0[8], a1[8];
#pragma unroll
    for (int j = 0; j < 8; ++j) { a0[j] = 0.f; a1[j] = 0.f; }
    int p = beg + ng;
    for (; p + 8 < end; p += 16) {
        int s0 = csr_src[p];
        int s1 = csr_src[p + 8];
        bf16x8 v0 = *(const bf16x8*)(Hl + (size_t)s0 * 64 + fl * 8);
        bf16x8 v1 = *(const bf16x8*)(Hl + (size_t)s1 * 64 + fl * 8);
#pragma unroll
        for (int j = 0; j < 8; ++j) { a0[j] += bf2f(v0[j]); a1[j] += bf2f(v1[j]); }
    }
    if (p < end) {
        int s0 = csr_src[p];
        bf16x8 v0 = *(const bf16x8*)(Hl + (size_t)s0 * 64 + fl * 8);
#pragma unroll
        for (int j = 0; j < 8; ++j) a0[j] += bf2f(v0[j]);
    }
#pragma unroll
    for (int j = 0; j < 8; ++j) a0[j] += a1[j];
#pragma unroll
    for (int m = 8; m < 64; m <<= 1)
#pragma unroll
        for (int j = 0; j < 8; ++j) a0[j] += __shfl_xor(a0[j], m, 64);
    if (ng == 0) {
        float idg = invdeg[node];
        const float4 h0 = *(const float4*)(Hr + (size_t)node * 64 + fl * 8);
        const float4 h1 = *(const float4*)(Hr + (size_t)node * 64 + fl * 8 + 4);
        short s[8];
        s[0] = f2bf(a0[0] * idg + bl[fl * 8 + 0] + h0.x);
        s[1] = f2bf(a0[1] * idg + bl[fl * 8 + 1] + h0.y);
        s[2] = f2bf(a0[2] * idg + bl[fl * 8 + 2] + h0.z);
        s[3] = f2bf(a0[3] * idg + bl[fl * 8 + 3] + h0.w);
        s[4] = f2bf(a0[4] * idg + bl[fl * 8 + 4] + h1.x);
        s[5] = f2bf(a0[5] * idg + bl[fl * 8 + 5] + h1.y);
        s[6] = f2bf(a0[6] * idg + bl[fl * 8 + 6] + h1.z);
        s[7] = f2bf(a0[7] * idg + bl[fl * 8 + 7] + h1.w);
        *(bf16x8*)(ebf + (size_t)node * 64 + fl * 8) = *(bf16x8*)s;
    }
}

// ---------- conv2/3 step 1: m_i = mean_{j->i} e_j (bf16 out) ----------
__launch_bounds__(256)
__global__ void gathermean_kernel(const int* __restrict__ row_ptr, const int* __restrict__ csr_src,
                                  const short* __restrict__ ein, const float* __restrict__ invdeg,
                                  short* __restrict__ m) {
    int node = blockIdx.x * 4 + (threadIdx.x >> 6);
    if (node >= NN) return;
    int lane = threadIdx.x & 63;
    int ng = lane >> 3;
    int fl = lane & 7;
    int beg = row_ptr[node], end = row_ptr[node + 1];
    float a0[8], a1[8];
#pragma unroll
    for (int j = 0; j < 8; ++j) { a0[j] = 0.f; a1[j] = 0.f; }
    int p = beg + ng;
    for (; p + 8 < end; p += 16) {
        int s0 = csr_src[p];
        int s1 = csr_src[p + 8];
        bf16x8 v0 = *(const bf16x8*)(ein + (size_t)s0 * 64 + fl * 8);
        bf16x8 v1 = *(const bf16x8*)(ein + (size_t)s1 * 64 + fl * 8);
#pragma unroll
        for (int j = 0; j < 8; ++j) { a0[j] += bf2f(v0[j]); a1[j] += bf2f(v1[j]); }
    }
    if (p < end) {
        int s0 = csr_src[p];
        bf16x8 v0 = *(const bf16x8*)(ein + (size_t)s0 * 64 + fl * 8);
#pragma unroll
        for (int j = 0; j < 8; ++j) a0[j] += bf2f(v0[j]);
    }
#pragma unroll
    for (int j = 0; j < 8; ++j) a0[j] += a1[j];
#pragma unroll
    for (int mm = 8; mm < 64; mm <<= 1)
#pragma unroll
        for (int j = 0; j < 8; ++j) a0[j] += __shfl_xor(a0[j], mm, 64);
    if (ng == 0) {
        float idg = invdeg[node];
        short s[8];
#pragma unroll
        for (int j = 0; j < 8; ++j) s[j] = f2bf(a0[j] * idg);
        *(bf16x8*)(m + (size_t)node * 64 + fl * 8) = *(bf16x8*)s;
    }
}

// ---------- conv2/3 step 2: out = m@Wl + e@Wr + bl (fused dual GEMM, K=64, in-place-safe) ----------
template<bool LAST>
__launch_bounds__(256)
__global__ void gemm_dual64(const short* __restrict__ m, const short* __restrict__ ein,
                            const short* __restrict__ Wbl, const short* __restrict__ Wbr,
                            const float* __restrict__ bl,
                            short* __restrict__ eout, float* __restrict__ e3out) {
    const int tid = threadIdx.x;
    const int row0 = blockIdx.x * 64;
    const int w = tid >> 6, l = tid & 63;
    const int q = l >> 4, r16 = l & 15;
    const int arow = row0 + w * 16 + r16;
    const bool ok = arow < NN;
    const short* mp = m   + (size_t)(ok ? arow : 0) * 64 + q * 8;
    const short* ep = ein + (size_t)(ok ? arow : 0) * 64 + q * 8;
    f32x4 acc[4];
#pragma unroll
    for (int c = 0; c < 4; ++c) acc[c] = (f32x4){0.f, 0.f, 0.f, 0.f};
    const bf16x8 z8 = (bf16x8){0, 0, 0, 0, 0, 0, 0, 0};
#pragma unroll
    for (int t = 0; t < 2; ++t) {
        bf16x8 am = ok ? *(const bf16x8*)(mp + t * 32) : z8;
        bf16x8 ae = ok ? *(const bf16x8*)(ep + t * 32) : z8;
#pragma unroll
        for (int c = 0; c < 4; ++c) {
            bf16x8 wl = *(const bf16x8*)(Wbl + (size_t)(c * 16 + r16) * 64 + t * 32 + q * 8);
            bf16x8 wr = *(const bf16x8*)(Wbr + (size_t)(c * 16 + r16) * 64 + t * 32 + q * 8);
            acc[c] = __builtin_amdgcn_mfma_f32_16x16x32_bf16(am, wl, acc[c], 0, 0, 0);
            acc[c] = __builtin_amdgcn_mfma_f32_16x16x32_bf16(ae, wr, acc[c], 0, 0, 0);
        }
    }
#pragma unroll
    for (int c = 0; c < 4; ++c) {
#pragma unroll
        for (int rr = 0; rr < 4; ++rr) {
            int grow = row0 + w * 16 + q * 4 + rr;
            int col = c * 16 + r16;
            if (grow < NN) {
                float o = acc[c][rr] + bl[col];
                if (LAST) e3out[(size_t)grow * 64 + col] = o;
                else      eout[(size_t)grow * 64 + col]  = f2bf(o);
            }
        }
    }
}

// ---------- pool: segment starts from sorted batch ----------
__global__ void gseg_kernel(const int* __restrict__ batch, int* __restrict__ gstart) {
    int i = blockIdx.x * blockDim.x + threadIdx.x;
    if (i >= NN) return;
    int bc = batch[i];
    int bp = (i == 0) ? -1 : batch[i - 1];
    for (int b = bp + 1; b <= bc; ++b) gstart[b] = i;
    if (i == NN - 1)
        for (int b = bc + 1; b <= NB; ++b) gstart[b] = NN;
}

// ---------- pool: segmented mean over fp32 e3 ----------
__launch_bounds__(256)
__global__ void pool_seg(const float* __restrict__ e, const int* __restrict__ gstart,
                         float* __restrict__ c0) {
    __shared__ float part[4][64];
    int b = blockIdx.x;
    int w = threadIdx.x >> 6, lane = threadIdx.x & 63;
    int s = gstart[b], t = gstart[b + 1];
    float acc = 0.f;
    for (int i = s + w; i < t; i += 4) acc += e[(size_t)i * 64 + lane];
    part[w][lane] = acc;
    __syncthreads();
    if (w == 0) {
        float v = part[0][lane] + part[1][lane] + part[2][lane] + part[3][lane];
        c0[b * 64 + lane] = v / fmaxf((float)(t - s), 1.0f);
    }
}

// ---------- MLP head ----------
__global__ void lin_kernel(const float* __restrict__ in, const float* __restrict__ W,
                           const float* __restrict__ bias, float* __restrict__ out,
                           int Kd, int Dout) {
    int id = blockIdx.x * blockDim.x + threadIdx.x;
    if (id >= NB * Dout) return;
    int row = id / Dout, col = id - row * Dout;
    const float* ir = in + (size_t)row * Kd;
    float acc = bias[col];
    for (int k = 0; k < Kd; ++k) acc += ir[k] * W[(size_t)k * Dout + col];
    out[id] = acc;
}

__global__ void bnstats_kernel(const float* __restrict__ c, const float* __restrict__ g,
                               const float* __restrict__ beta, float* __restrict__ sa,
                               float* __restrict__ sb, int Dout) {
    int col = blockIdx.x;
    int tid = threadIdx.x;
    float s = 0.f, sq = 0.f;
    for (int r = tid; r < NB; r += 256) {
        float v = c[(size_t)r * Dout + col];
        s += v; sq += v * v;
    }
    __shared__ float ls[256], lq[256];
    ls[tid] = s; lq[tid] = sq;
    __syncthreads();
    for (int o = 128; o > 0; o >>= 1) {
        if (tid < o) { ls[tid] += ls[tid + o]; lq[tid] += lq[tid + o]; }
        __syncthreads();
    }
    if (tid == 0) {
        float mu = ls[0] / NB;
        float var = lq[0] / NB - mu * mu;
        float a = g[col] * rsqrtf(var + 1e-5f);
        sa[col] = a;
        sb[col] = beta[col] - mu * a;
    }
}

__global__ void bnapply_kernel(const float* __restrict__ c, const float* __restrict__ sa,
                               const float* __restrict__ sb, float* __restrict__ bv, int Dout) {
    int id = blockIdx.x * blockDim.x + threadIdx.x;
    if (id >= NB * Dout) return;
    int col = id % Dout;
    bv[id] = tanhf(c[id] * sa[col] + sb[col]);
}

extern "C" void kernel_launch(void* const* d_in, const int* in_sizes, int n_in,
                              void* d_out, int out_size, void* d_ws, size_t ws_size,
                              hipStream_t stream) {
    const float* x    = (const float*)d_in[0];
    const int* ei     = (const int*)d_in[1];
    const int* src    = ei;
    const int* dst    = ei + NE;
    const int* batch  = (const int*)d_in[2];
    const float* c1Wl = (const float*)d_in[4];
    const float* c1bl = (const float*)d_in[5];
    const float* c1Wr = (const float*)d_in[6];
    const float* c2Wl = (const float*)d_in[7];
    const float* c2bl = (const float*)d_in[8];
    const float* c2Wr = (const float*)d_in[9];
    const float* c3Wl = (const float*)d_in[10];
    const float* c3bl = (const float*)d_in[11];
    const float* c3Wr = (const float*)d_in[12];
    const float* l1W  = (const float*)d_in[13]; const float* l1b = (const float*)d_in[14];
    const float* bn1g = (const float*)d_in[15]; const float* bn1b = (const float*)d_in[16];
    const float* l2W  = (const float*)d_in[17]; const float* l2b = (const float*)d_in[18];
    const float* bn2g = (const float*)d_in[19]; const float* bn2b = (const float*)d_in[20];
    const float* l3W  = (const float*)d_in[21]; const float* l3b = (const float*)d_in[22];
    const float* bn3g = (const float*)d_in[23]; const float* bn3b = (const float*)d_in[24];
    const float* l4W  = (const float*)d_in[25]; const float* l4b = (const float*)d_in[26];
    float* out = (float*)d_out;

    char* wsb = (char*)d_ws;
    short* Hl     = (short*)wsb; wsb += (size_t)NN * 64 * 2;
    float* Hr     = (float*)wsb; wsb += (size_t)NN * 64 * 4;
    short* e      = (short*)wsb; wsb += (size_t)NN * 64 * 2;
    short* m      = (short*)wsb; wsb += (size_t)NN * 64 * 2;
    float* e3     = (float*)wsb; wsb += (size_t)NN * 64 * 4;
    float* invdeg = (float*)wsb; wsb += (size_t)NN * 4;
    float* c      = (float*)wsb; wsb += (size_t)NB * HIDN * 4;
    float* bv     = (float*)wsb; wsb += (size_t)NB * HIDN * 4;
    float* sa     = (float*)wsb; wsb += HIDN * 4;
    float* sb     = (float*)wsb; wsb += HIDN * 4;
    short* Wf1    = (short*)wsb; wsb += 16 * 8 * 64 * 8 * 2;   // 128 KB fragment-major
    short* Wb2l   = (short*)wsb; wsb += 64 * 64 * 2;
    short* Wb2r   = (short*)wsb; wsb += 64 * 64 * 2;
    short* Wb3l   = (short*)wsb; wsb += 64 * 64 * 2;
    short* Wb3r   = (short*)wsb; wsb += 64 * 64 * 2;
    int* row_ptr  = (int*)wsb;   wsb += (size_t)(NN + 1) * 4;
    int* csr_src  = (int*)wsb;   wsb += (size_t)NE * 4;
    int* buk_base = (int*)wsb;   wsb += (NBUK + 1) * 4;
    int* gstart   = (int*)wsb;   wsb += (NB + 1) * 4;
    // scratch aliased into buffers dead during CSR build:
    int* bpack      = (int*)Hl;  // NE ints = 12.8 MB == sizeof(Hl)
    int* block_hist = (int*)e;   // 200 KB

    // ---- CSR build: bucketed counting sort ----
    bukhist_kernel<<<NBLK_E, 256, 0, stream>>>(dst, block_hist);
    bukoff_kernel<<<1, NBUK, 0, stream>>>(block_hist, buk_base);
    bukscat_kernel<<<NBLK_E, 256, 0, stream>>>(src, dst, block_hist, bpack);
    bukfin_kernel<<<NBUK, 256, 0, stream>>>(buk_base, bpack, row_ptr, invdeg, csr_src);

    // ---- graph segment table ----
    gseg_kernel<<<(NN + 255) / 256, 256, 0, stream>>>(batch, gstart);

    // ---- weight prep ----
    wprep_frag<<<(16 * 8 * 64 + 255) / 256, 256, 0, stream>>>(c1Wl, c1Wr, Wf1);
    wprep64<<<(64 * 64 + 255) / 256, 256, 0, stream>>>(c2Wl, Wb2l);
    wprep64<<<(64 * 64 + 255) / 256, 256, 0, stream>>>(c2Wr, Wb2r);
    wprep64<<<(64 * 64 + 255) / 256, 256, 0, stream>>>(c3Wl, Wb3l);
    wprep64<<<(64 * 64 + 255) / 256, 256, 0, stream>>>(c3Wr, Wb3r);

    const int GB64 = (NN + 63) / 64;
    const int GGB  = (NN + 3) / 4;

    // conv1: GEMM then gather+combine
    gemm_direct2<<<GB64, 256, 0, stream>>>(x, Wf1, Hl, Hr);
    gather_kernel<<<GGB, 256, 0, stream>>>(row_ptr, csr_src, Hl, Hr, invdeg, c1bl, e);
    // conv2: gather-mean then fused dual GEMM (in-place on e)
    gathermean_kernel<<<GGB, 256, 0, stream>>>(row_ptr, csr_src, e, invdeg, m);
    gemm_dual64<false><<<GB64, 256, 0, stream>>>(m, e, Wb2l, Wb2r, c2bl, e, nullptr);
    // conv3
    gathermean_kernel<<<GGB, 256, 0, stream>>>(row_ptr, csr_src, e, invdeg, m);
    gemm_dual64<true><<<GB64, 256, 0, stream>>>(m, e, Wb3l, Wb3r, c3bl, nullptr, e3);

    // pool -> bv holds c0 [512,64] fp32
    pool_seg<<<NB, 256, 0, stream>>>(e3, gstart, bv);

    // head
    lin_kernel<<<(NB * 200 + 255) / 256, 256, 0, stream>>>(bv, l1W, l1b, c, 64, 200);
    bnstats_kernel<<<200, 256, 0, stream>>>(c, bn1g, bn1b, sa, sb, 200);
    bnapply_kernel<<<(NB * 200 + 255) / 256, 256, 0, stream>>>(c, sa, sb, bv, 200);

    lin_kernel<<<(NB * 100 + 255) / 256, 256, 0, stream>>>(bv, l2W, l2b, c, 200, 100);
    bnstats_kernel<<<100, 256, 0, stream>>>(c, bn2g, bn2b, sa, sb, 100);
    bnapply_kernel<<<(NB * 100 + 255) / 256, 256, 0, stream>>>(c, sa, sb, bv, 100);

    lin_kernel<<<(NB * 100 + 255) / 256, 256, 0, stream>>>(bv, l3W, l3b, c, 100, 100);
    bnstats_kernel<<<100, 256, 0, stream>>>(c, bn3g, bn3b, sa, sb, 100);
    bnapply_kernel<<<(NB * 100 + 255) / 256, 256, 0, stream>>>(c, sa, sb, bv, 100);

    lin_kernel<<<(NB * 80 + 255) / 256, 256, 0, stream>>>(bv, l4W, l4b, out, 100, 80);
}

// Round 15
// 601.415 us; speedup vs baseline: 1.0202x; 1.0202x over previous
//
#include <hip/hip_runtime.h>
#include <hip/hip_bf16.h>

#define NN 100000
#define NE 3200000
#define NB 512
#define DIN 500
#define DH 64
#define HIDN 200
#define NCLS 80

#define NBUK 256
#define NPB 391
#define EPB 16384
#define NBLK_E ((NE + EPB - 1) / EPB)   // 196

typedef __attribute__((ext_vector_type(8))) short bf16x8;
typedef __attribute__((ext_vector_type(4))) float f32x4;

__device__ __forceinline__ short f2bf(float f) {
    union { float f; unsigned u; } v; v.f = f;
    unsigned r = v.u + 0x7FFF + ((v.u >> 16) & 1);   // RNE
    return (short)(r >> 16);
}
__device__ __forceinline__ float bf2f(short s) {
    union { unsigned u; float f; } v; v.u = ((unsigned)(unsigned short)s) << 16;
    return v.f;
}

// ---------- CSR pass A: per-block bucket histogram ----------
__global__ void bukhist_kernel(const int* __restrict__ dst, int* __restrict__ block_hist) {
    __shared__ int h[NBUK];
    for (int i = threadIdx.x; i < NBUK; i += 256) h[i] = 0;
    __syncthreads();
    int base = blockIdx.x * EPB;
    int end = min(base + EPB, NE);
    for (int e = base + threadIdx.x; e < end; e += 256)
        atomicAdd(&h[dst[e] / NPB], 1);
    __syncthreads();
    for (int i = threadIdx.x; i < NBUK; i += 256)
        block_hist[blockIdx.x * NBUK + i] = h[i];
}

// ---------- CSR pass B ----------
__global__ void bukoff_kernel(int* __restrict__ block_hist, int* __restrict__ buk_base) {
    __shared__ int tot[NBUK];
    __shared__ int sc[NBUK];
    int b = threadIdx.x;
    int s = 0;
    for (int i = 0; i < NBLK_E; ++i) s += block_hist[i * NBUK + b];
    tot[b] = s; sc[b] = s;
    __syncthreads();
    for (int o = 1; o < NBUK; o <<= 1) {
        int t = (b >= o) ? sc[b - o] : 0;
        __syncthreads();
        sc[b] += t;
        __syncthreads();
    }
    int excl = sc[b] - tot[b];
    buk_base[b] = excl;
    if (b == NBUK - 1) buk_base[NBUK] = excl + tot[b];
    int run = excl;
    for (int i = 0; i < NBLK_E; ++i) {
        int idx = i * NBUK + b;
        int v = block_hist[idx];
        block_hist[idx] = run;
        run += v;
    }
}

// ---------- CSR pass C ----------
__global__ void bukscat_kernel(const int* __restrict__ src, const int* __restrict__ dst,
                               const int* __restrict__ block_hist, int* __restrict__ bpack) {
    __shared__ int cur[NBUK];
    for (int i = threadIdx.x; i < NBUK; i += 256)
        cur[i] = block_hist[blockIdx.x * NBUK + i];
    __syncthreads();
    int base = blockIdx.x * EPB;
    int end = min(base + EPB, NE);
    for (int e = base + threadIdx.x; e < end; e += 256) {
        int d = dst[e];
        int bk = d / NPB;
        int p = atomicAdd(&cur[bk], 1);
        bpack[p] = (src[e] << 9) | (d - bk * NPB);
    }
}

// ---------- CSR pass D ----------
__global__ void bukfin_kernel(const int* __restrict__ buk_base, const int* __restrict__ bpack,
                              int* __restrict__ row_ptr, float* __restrict__ invdeg,
                              int* __restrict__ csr_src) {
    __shared__ int cnt[NPB];
    __shared__ int cbase[NPB];
    int bk = blockIdx.x;
    int n0 = bk * NPB;
    int nloc = min(n0 + NPB, NN) - n0;
    for (int i = threadIdx.x; i < nloc; i += 256) cnt[i] = 0;
    __syncthreads();
    int beg = buk_base[bk], end = buk_base[bk + 1];
    for (int p = beg + threadIdx.x; p < end; p += 256)
        atomicAdd(&cnt[bpack[p] & 511], 1);
    __syncthreads();
    if (threadIdx.x == 0) {
        int run = beg;
        for (int i = 0; i < nloc; ++i) { int v = cnt[i]; cbase[i] = run; run += v; }
    }
    __syncthreads();
    for (int i = threadIdx.x; i < nloc; i += 256) {
        row_ptr[n0 + i] = cbase[i];
        invdeg[n0 + i] = 1.0f / fmaxf((float)cnt[i], 1.0f);
        cnt[i] = cbase[i];
    }
    if (bk == NBUK - 1 && threadIdx.x == 0) row_ptr[NN] = end;
    __syncthreads();
    for (int p = beg + threadIdx.x; p < end; p += 256) {
        int v = bpack[p];
        int q = atomicAdd(&cnt[v & 511], 1);
        csr_src[q] = v >> 9;
    }
}

// ---------- W1 prep: fragment-major. Wf[((t*8+c)*64 + lane)*8 + i] = W[k][col],
// k = t*32 + (lane>>4)*8 + i, col = c*16 + (lane&15). Each (t,c) frag = 1KB contiguous. ----------
__global__ void wprep_frag(const float* __restrict__ Wl, const float* __restrict__ Wr,
                           short* __restrict__ Wf) {
    int id = blockIdx.x * blockDim.x + threadIdx.x;   // 16*8*64 = 8192
    if (id >= 16 * 8 * 64) return;
    int l = id & 63;
    int c = (id >> 6) & 7;
    int t = id >> 9;
    int q = l >> 4, r16 = l & 15;
    int col = c * 16 + r16;
    short v[8];
#pragma unroll
    for (int i = 0; i < 8; ++i) {
        int k = t * 32 + q * 8 + i;
        float f = 0.f;
        if (k < DIN) f = (col < 64) ? Wl[(size_t)k * 64 + col] : Wr[(size_t)k * 64 + (col - 64)];
        v[i] = f2bf(f);
    }
    *(bf16x8*)(Wf + (size_t)id * 8) = *(bf16x8*)v;
}

// ---------- W prep 64x64: Wb[col][k] ----------
__global__ void wprep64(const float* __restrict__ W, short* __restrict__ Wb) {
    int id = blockIdx.x * blockDim.x + threadIdx.x;
    if (id >= 64 * 64) return;
    int col = id >> 6, k = id & 63;
    Wb[col * 64 + k] = f2bf(W[(size_t)k * 64 + col]);
}

// ---------- conv1: split-K x2 direct MFMA. Block = 32 rows x 4 waves.
// wave (g,h): row-group g (16 rows), K-half h (256 of 512). 8 steps/wave, LDS combine. ----------
__launch_bounds__(256)
__global__ void gemm_splitk(const float* __restrict__ in, const short* __restrict__ Wf,
                            short* __restrict__ Hl, float* __restrict__ Hr) {
    __shared__ float red[2][64][36];   // [row-group][lane][32 acc + pabs]
    const int tid = threadIdx.x;
    const int w = tid >> 6, l = tid & 63;
    const int g = w >> 1;              // row-group
    const int h = w & 1;               // K-half
    const int q = l >> 4, r16 = l & 15;
    const int tile0 = blockIdx.x * 32 + g * 16;
    const int arow_i = tile0 + r16;
    const bool ok = arow_i < NN;
    const float* arow = in + (size_t)(ok ? arow_i : 0) * DIN + h * 256 + q * 8;
    // K-half h skips h*8 steps x 8 frags x 512 shorts = h*32768 shorts  [FIXED: was /8 bug]
    const short* wf = Wf + (size_t)l * 8 + (size_t)h * 8 * 8 * 512;

    f32x4 acc[8];
#pragma unroll
    for (int c = 0; c < 8; ++c) acc[c] = (f32x4){0.f, 0.f, 0.f, 0.f};
    float pabs = 0.f;

#pragma unroll 2
    for (int t = 0; t < 8; ++t) {
        float v[8];
        if (h == 0 || t < 7) {
            const float4 f0 = *(const float4*)(arow + t * 32);
            const float4 f1 = *(const float4*)(arow + t * 32 + 4);
            v[0] = f0.x; v[1] = f0.y; v[2] = f0.z; v[3] = f0.w;
            v[4] = f1.x; v[5] = f1.y; v[6] = f1.z; v[7] = f1.w;
        } else {   // h=1, t=7: k = 480 + q*8 + i, guard k < 500
#pragma unroll
            for (int i = 0; i < 8; ++i) {
                int gk = 256 + t * 32 + q * 8 + i;
                v[i] = (gk < DIN) ? arow[t * 32 + i] : 0.f;
            }
        }
        short sh[8];
#pragma unroll
        for (int i = 0; i < 8; ++i) { pabs += fabsf(v[i]); sh[i] = f2bf(v[i]); }
        bf16x8 a = *(bf16x8*)sh;
#pragma unroll
        for (int c = 0; c < 8; ++c) {
            bf16x8 b = *(const bf16x8*)(wf + ((size_t)(t * 8 + c) << 9));
            acc[c] = __builtin_amdgcn_mfma_f32_16x16x32_bf16(a, b, acc[c], 0, 0, 0);
        }
    }

    // combine K-halves: h=1 dumps to LDS; h=0 adds
    if (h == 1) {
#pragma unroll
        for (int c = 0; c < 8; ++c) *(f32x4*)&red[g][l][c * 4] = acc[c];
        red[g][l][32] = pabs;
    }
    __syncthreads();
    if (h == 0) {
#pragma unroll
        for (int c = 0; c < 8; ++c) {
            f32x4 o = *(f32x4*)&red[g][l][c * 4];
            acc[c][0] += o[0]; acc[c][1] += o[1]; acc[c][2] += o[2]; acc[c][3] += o[3];
        }
        pabs += red[g][l][32];
        // per-row L1 inverse norm: sum 4 k-chunk lanes of each row (xor lane bits 4,5)
        pabs += __shfl_xor(pabs, 16, 64);
        pabs += __shfl_xor(pabs, 32, 64);
        float sval = 1.0f / fmaxf(pabs, 1e-12f);
#pragma unroll
        for (int rr = 0; rr < 4; ++rr) {
            int lrow = q * 4 + rr;             // C/D: row=(lane>>4)*4+reg, col=lane&15
            float srow = __shfl(sval, lrow, 64);
            int grow = tile0 + lrow;
            if (grow < NN) {
#pragma unroll
                for (int c = 0; c < 8; ++c) {
                    float o = acc[c][rr] * srow;
                    if (c < 4) Hl[(size_t)grow * 64 + c * 16 + r16] = f2bf(o);
                    else       Hr[(size_t)grow * 64 + (c - 4) * 16 + r16] = o;
                }
            }
        }
    }
}

// ---------- conv1 gather + combine: e = sum(Hl_j)*invdeg + bl + Hr_i (bf16 out) ----------
__launch_bounds__(256)
__global__ void gather_kernel(const int* __restrict__ row_ptr, const int* __restrict__ csr_src,
                              const short* __restrict__ Hl, const float* __restrict__ Hr,
                              const float* __restrict__ invdeg, const float* __restrict__ bl,
                              short* __restrict__ ebf) {
    int node = blockIdx.x * 4 + (threadIdx.x >> 6);
    if (node >= NN) return;
    int lane = threadIdx.x & 63;
    int ng = lane >> 3;
    int fl = lane & 7;
    int beg = row_ptr[node], end = row_ptr[node + 1];
    float a0[8], a1[8];
#pragma unroll
    for (int j = 0; j < 8; ++j) { a0[j] = 0.f; a1[j] = 0.f; }
    int p = beg + ng;
    for (; p + 8 < end; p += 16) {
        int s0 = csr_src[p];
        int s1 = csr_src[p + 8];
        bf16x8 v0 = *(const bf16x8*)(Hl + (size_t)s0 * 64 + fl * 8);
        bf16x8 v1 = *(const bf16x8*)(Hl + (size_t)s1 * 64 + fl * 8);
#pragma unroll
        for (int j = 0; j < 8; ++j) { a0[j] += bf2f(v0[j]); a1[j] += bf2f(v1[j]); }
    }
    if (p < end) {
        int s0 = csr_src[p];
        bf16x8 v0 = *(const bf16x8*)(Hl + (size_t)s0 * 64 + fl * 8);
#pragma unroll
        for (int j = 0; j < 8; ++j) a0[j] += bf2f(v0[j]);
    }
#pragma unroll
    for (int j = 0; j < 8; ++j) a0[j] += a1[j];
#pragma unroll
    for (int m = 8; m < 64; m <<= 1)
#pragma unroll
        for (int j = 0; j < 8; ++j) a0[j] += __shfl_xor(a0[j], m, 64);
    if (ng == 0) {
        float idg = invdeg[node];
        const float4 h0 = *(const float4*)(Hr + (size_t)node * 64 + fl * 8);
        const float4 h1 = *(const float4*)(Hr + (size_t)node * 64 + fl * 8 + 4);
        short s[8];
        s[0] = f2bf(a0[0] * idg + bl[fl * 8 + 0] + h0.x);
        s[1] = f2bf(a0[1] * idg + bl[fl * 8 + 1] + h0.y);
        s[2] = f2bf(a0[2] * idg + bl[fl * 8 + 2] + h0.z);
        s[3] = f2bf(a0[3] * idg + bl[fl * 8 + 3] + h0.w);
        s[4] = f2bf(a0[4] * idg + bl[fl * 8 + 4] + h1.x);
        s[5] = f2bf(a0[5] * idg + bl[fl * 8 + 5] + h1.y);
        s[6] = f2bf(a0[6] * idg + bl[fl * 8 + 6] + h1.z);
        s[7] = f2bf(a0[7] * idg + bl[fl * 8 + 7] + h1.w);
        *(bf16x8*)(ebf + (size_t)node * 64 + fl * 8) = *(bf16x8*)s;
    }
}

// ---------- conv2/3 step 1: m_i = mean_{j->i} e_j (bf16 out) ----------
__launch_bounds__(256)
__global__ void gathermean_kernel(const int* __restrict__ row_ptr, const int* __restrict__ csr_src,
                                  const short* __restrict__ ein, const float* __restrict__ invdeg,
                                  short* __restrict__ m) {
    int node = blockIdx.x * 4 + (threadIdx.x >> 6);
    if (node >= NN) return;
    int lane = threadIdx.x & 63;
    int ng = lane >> 3;
    int fl = lane & 7;
    int beg = row_ptr[node], end = row_ptr[node + 1];
    float a0[8], a1[8];
#pragma unroll
    for (int j = 0; j < 8; ++j) { a0[j] = 0.f; a1[j] = 0.f; }
    int p = beg + ng;
    for (; p + 8 < end; p += 16) {
        int s0 = csr_src[p];
        int s1 = csr_src[p + 8];
        bf16x8 v0 = *(const bf16x8*)(ein + (size_t)s0 * 64 + fl * 8);
        bf16x8 v1 = *(const bf16x8*)(ein + (size_t)s1 * 64 + fl * 8);
#pragma unroll
        for (int j = 0; j < 8; ++j) { a0[j] += bf2f(v0[j]); a1[j] += bf2f(v1[j]); }
    }
    if (p < end) {
        int s0 = csr_src[p];
        bf16x8 v0 = *(const bf16x8*)(ein + (size_t)s0 * 64 + fl * 8);
#pragma unroll
        for (int j = 0; j < 8; ++j) a0[j] += bf2f(v0[j]);
    }
#pragma unroll
    for (int j = 0; j < 8; ++j) a0[j] += a1[j];
#pragma unroll
    for (int mm = 8; mm < 64; mm <<= 1)
#pragma unroll
        for (int j = 0; j < 8; ++j) a0[j] += __shfl_xor(a0[j], mm, 64);
    if (ng == 0) {
        float idg = invdeg[node];
        short s[8];
#pragma unroll
        for (int j = 0; j < 8; ++j) s[j] = f2bf(a0[j] * idg);
        *(bf16x8*)(m + (size_t)node * 64 + fl * 8) = *(bf16x8*)s;
    }
}

// ---------- conv2/3 step 2: out = m@Wl + e@Wr + bl (fused dual GEMM, K=64, in-place-safe) ----------
template<bool LAST>
__launch_bounds__(256)
__global__ void gemm_dual64(const short* __restrict__ m, const short* __restrict__ ein,
                            const short* __restrict__ Wbl, const short* __restrict__ Wbr,
                            const float* __restrict__ bl,
                            short* __restrict__ eout, float* __restrict__ e3out) {
    const int tid = threadIdx.x;
    const int row0 = blockIdx.x * 64;
    const int w = tid >> 6, l = tid & 63;
    const int q = l >> 4, r16 = l & 15;
    const int arow = row0 + w * 16 + r16;
    const bool ok = arow < NN;
    const short* mp = m   + (size_t)(ok ? arow : 0) * 64 + q * 8;
    const short* ep = ein + (size_t)(ok ? arow : 0) * 64 + q * 8;
    f32x4 acc[4];
#pragma unroll
    for (int c = 0; c < 4; ++c) acc[c] = (f32x4){0.f, 0.f, 0.f, 0.f};
    const bf16x8 z8 = (bf16x8){0, 0, 0, 0, 0, 0, 0, 0};
#pragma unroll
    for (int t = 0; t < 2; ++t) {
        bf16x8 am = ok ? *(const bf16x8*)(mp + t * 32) : z8;
        bf16x8 ae = ok ? *(const bf16x8*)(ep + t * 32) : z8;
#pragma unroll
        for (int c = 0; c < 4; ++c) {
            bf16x8 wl = *(const bf16x8*)(Wbl + (size_t)(c * 16 + r16) * 64 + t * 32 + q * 8);
            bf16x8 wr = *(const bf16x8*)(Wbr + (size_t)(c * 16 + r16) * 64 + t * 32 + q * 8);
            acc[c] = __builtin_amdgcn_mfma_f32_16x16x32_bf16(am, wl, acc[c], 0, 0, 0);
            acc[c] = __builtin_amdgcn_mfma_f32_16x16x32_bf16(ae, wr, acc[c], 0, 0, 0);
        }
    }
#pragma unroll
    for (int c = 0; c < 4; ++c) {
#pragma unroll
        for (int rr = 0; rr < 4; ++rr) {
            int grow = row0 + w * 16 + q * 4 + rr;
            int col = c * 16 + r16;
            if (grow < NN) {
                float o = acc[c][rr] + bl[col];
                if (LAST) e3out[(size_t)grow * 64 + col] = o;
                else      eout[(size_t)grow * 64 + col]  = f2bf(o);
            }
        }
    }
}

// ---------- pool: segment starts from sorted batch ----------
__global__ void gseg_kernel(const int* __restrict__ batch, int* __restrict__ gstart) {
    int i = blockIdx.x * blockDim.x + threadIdx.x;
    if (i >= NN) return;
    int bc = batch[i];
    int bp = (i == 0) ? -1 : batch[i - 1];
    for (int b = bp + 1; b <= bc; ++b) gstart[b] = i;
    if (i == NN - 1)
        for (int b = bc + 1; b <= NB; ++b) gstart[b] = NN;
}

// ---------- pool: segmented mean over fp32 e3 ----------
__launch_bounds__(256)
__global__ void pool_seg(const float* __restrict__ e, const int* __restrict__ gstart,
                         float* __restrict__ c0) {
    __shared__ float part[4][64];
    int b = blockIdx.x;
    int w = threadIdx.x >> 6, lane = threadIdx.x & 63;
    int s = gstart[b], t = gstart[b + 1];
    float acc = 0.f;
    for (int i = s + w; i < t; i += 4) acc += e[(size_t)i * 64 + lane];
    part[w][lane] = acc;
    __syncthreads();
    if (w == 0) {
        float v = part[0][lane] + part[1][lane] + part[2][lane] + part[3][lane];
        c0[b * 64 + lane] = v / fmaxf((float)(t - s), 1.0f);
    }
}

// ---------- MLP head ----------
__global__ void lin_kernel(const float* __restrict__ in, const float* __restrict__ W,
                           const float* __restrict__ bias, float* __restrict__ out,
                           int Kd, int Dout) {
    int id = blockIdx.x * blockDim.x + threadIdx.x;
    if (id >= NB * Dout) return;
    int row = id / Dout, col = id - row * Dout;
    const float* ir = in + (size_t)row * Kd;
    float acc = bias[col];
    for (int k = 0; k < Kd; ++k) acc += ir[k] * W[(size_t)k * Dout + col];
    out[id] = acc;
}

__global__ void bnstats_kernel(const float* __restrict__ c, const float* __restrict__ g,
                               const float* __restrict__ beta, float* __restrict__ sa,
                               float* __restrict__ sb, int Dout) {
    int col = blockIdx.x;
    int tid = threadIdx.x;
    float s = 0.f, sq = 0.f;
    for (int r = tid; r < NB; r += 256) {
        float v = c[(size_t)r * Dout + col];
        s += v; sq += v * v;
    }
    __shared__ float ls[256], lq[256];
    ls[tid] = s; lq[tid] = sq;
    __syncthreads();
    for (int o = 128; o > 0; o >>= 1) {
        if (tid < o) { ls[tid] += ls[tid + o]; lq[tid] += lq[tid + o]; }
        __syncthreads();
    }
    if (tid == 0) {
        float mu = ls[0] / NB;
        float var = lq[0] / NB - mu * mu;
        float a = g[col] * rsqrtf(var + 1e-5f);
        sa[col] = a;
        sb[col] = beta[col] - mu * a;
    }
}

__global__ void bnapply_kernel(const float* __restrict__ c, const float* __restrict__ sa,
                               const float* __restrict__ sb, float* __restrict__ bv, int Dout) {
    int id = blockIdx.x * blockDim.x + threadIdx.x;
    if (id >= NB * Dout) return;
    int col = id % Dout;
    bv[id] = tanhf(c[id] * sa[col] + sb[col]);
}

extern "C" void kernel_launch(void* const* d_in, const int* in_sizes, int n_in,
                              void* d_out, int out_size, void* d_ws, size_t ws_size,
                              hipStream_t stream) {
    const float* x    = (const float*)d_in[0];
    const int* ei     = (const int*)d_in[1];
    const int* src    = ei;
    const int* dst    = ei + NE;
    const int* batch  = (const int*)d_in[2];
    const float* c1Wl = (const float*)d_in[4];
    const float* c1bl = (const float*)d_in[5];
    const float* c1Wr = (const float*)d_in[6];
    const float* c2Wl = (const float*)d_in[7];
    const float* c2bl = (const float*)d_in[8];
    const float* c2Wr = (const float*)d_in[9];
    const float* c3Wl = (const float*)d_in[10];
    const float* c3bl = (const float*)d_in[11];
    const float* c3Wr = (const float*)d_in[12];
    const float* l1W  = (const float*)d_in[13]; const float* l1b = (const float*)d_in[14];
    const float* bn1g = (const float*)d_in[15]; const float* bn1b = (const float*)d_in[16];
    const float* l2W  = (const float*)d_in[17]; const float* l2b = (const float*)d_in[18];
    const float* bn2g = (const float*)d_in[19]; const float* bn2b = (const float*)d_in[20];
    const float* l3W  = (const float*)d_in[21]; const float* l3b = (const float*)d_in[22];
    const float* bn3g = (const float*)d_in[23]; const float* bn3b = (const float*)d_in[24];
    const float* l4W  = (const float*)d_in[25]; const float* l4b = (const float*)d_in[26];
    float* out = (float*)d_out;

    char* wsb = (char*)d_ws;
    short* Hl     = (short*)wsb; wsb += (size_t)NN * 64 * 2;
    float* Hr     = (float*)wsb; wsb += (size_t)NN * 64 * 4;
    short* e      = (short*)wsb; wsb += (size_t)NN * 64 * 2;
    short* m      = (short*)wsb; wsb += (size_t)NN * 64 * 2;
    float* e3     = (float*)wsb; wsb += (size_t)NN * 64 * 4;
    float* invdeg = (float*)wsb; wsb += (size_t)NN * 4;
    float* c      = (float*)wsb; wsb += (size_t)NB * HIDN * 4;
    float* bv     = (float*)wsb; wsb += (size_t)NB * HIDN * 4;
    float* sa     = (float*)wsb; wsb += HIDN * 4;
    float* sb     = (float*)wsb; wsb += HIDN * 4;
    short* Wf1    = (short*)wsb; wsb += 16 * 8 * 64 * 8 * 2;   // 128 KB fragment-major
    short* Wb2l   = (short*)wsb; wsb += 64 * 64 * 2;
    short* Wb2r   = (short*)wsb; wsb += 64 * 64 * 2;
    short* Wb3l   = (short*)wsb; wsb += 64 * 64 * 2;
    short* Wb3r   = (short*)wsb; wsb += 64 * 64 * 2;
    int* row_ptr  = (int*)wsb;   wsb += (size_t)(NN + 1) * 4;
    int* csr_src  = (int*)wsb;   wsb += (size_t)NE * 4;
    int* buk_base = (int*)wsb;   wsb += (NBUK + 1) * 4;
    int* gstart   = (int*)wsb;   wsb += (NB + 1) * 4;
    // scratch aliased into buffers dead during CSR build:
    int* bpack      = (int*)Hl;  // NE ints = 12.8 MB == sizeof(Hl)
    int* block_hist = (int*)e;   // 200 KB

    // ---- CSR build: bucketed counting sort ----
    bukhist_kernel<<<NBLK_E, 256, 0, stream>>>(dst, block_hist);
    bukoff_kernel<<<1, NBUK, 0, stream>>>(block_hist, buk_base);
    bukscat_kernel<<<NBLK_E, 256, 0, stream>>>(src, dst, block_hist, bpack);
    bukfin_kernel<<<NBUK, 256, 0, stream>>>(buk_base, bpack, row_ptr, invdeg, csr_src);

    // ---- graph segment table ----
    gseg_kernel<<<(NN + 255) / 256, 256, 0, stream>>>(batch, gstart);

    // ---- weight prep ----
    wprep_frag<<<(16 * 8 * 64 + 255) / 256, 256, 0, stream>>>(c1Wl, c1Wr, Wf1);
    wprep64<<<(64 * 64 + 255) / 256, 256, 0, stream>>>(c2Wl, Wb2l);
    wprep64<<<(64 * 64 + 255) / 256, 256, 0, stream>>>(c2Wr, Wb2r);
    wprep64<<<(64 * 64 + 255) / 256, 256, 0, stream>>>(c3Wl, Wb3l);
    wprep64<<<(64 * 64 + 255) / 256, 256, 0, stream>>>(c3Wr, Wb3r);

    const int GB32 = (NN + 31) / 32;
    const int GB64 = (NN + 63) / 64;
    const int GGB  = (NN + 3) / 4;

    // conv1: split-K GEMM then gather+combine
    gemm_splitk<<<GB32, 256, 0, stream>>>(x, Wf1, Hl, Hr);
    gather_kernel<<<GGB, 256, 0, stream>>>(row_ptr, csr_src, Hl, Hr, invdeg, c1bl, e);
    // conv2: gather-mean then fused dual GEMM (in-place on e)
    gathermean_kernel<<<GGB, 256, 0, stream>>>(row_ptr, csr_src, e, invdeg, m);
    gemm_dual64<false><<<GB64, 256, 0, stream>>>(m, e, Wb2l, Wb2r, c2bl, e, nullptr);
    // conv3
    gathermean_kernel<<<GGB, 256, 0, stream>>>(row_ptr, csr_src, e, invdeg, m);
    gemm_dual64<true><<<GB64, 256, 0, stream>>>(m, e, Wb3l, Wb3r, c3bl, nullptr, e3);

    // pool -> bv holds c0 [512,64] fp32
    pool_seg<<<NB, 256, 0, stream>>>(e3, gstart, bv);

    // head
    lin_kernel<<<(NB * 200 + 255) / 256, 256, 0, stream>>>(bv, l1W, l1b, c, 64, 200);
    bnstats_kernel<<<200, 256, 0, stream>>>(c, bn1g, bn1b, sa, sb, 200);
    bnapply_kernel<<<(NB * 200 + 255) / 256, 256, 0, stream>>>(c, sa, sb, bv, 200);

    lin_kernel<<<(NB * 100 + 255) / 256, 256, 0, stream>>>(bv, l2W, l2b, c, 200, 100);
    bnstats_kernel<<<100, 256, 0, stream>>>(c, bn2g, bn2b, sa, sb, 100);
    bnapply_kernel<<<(NB * 100 + 255) / 256, 256, 0, stream>>>(c, sa, sb, bv, 100);

    lin_kernel<<<(NB * 100 + 255) / 256, 256, 0, stream>>>(bv, l3W, l3b, c, 100, 100);
    bnstats_kernel<<<100, 256, 0, stream>>>(c, bn3g, bn3b, sa, sb, 100);
    bnapply_kernel<<<(NB * 100 + 255) / 256, 256, 0, stream>>>(c, sa, sb, bv, 100);

    lin_kernel<<<(NB * 80 + 255) / 256, 256, 0, stream>>>(bv, l4W, l4b, out, 100, 80);
}